// Round 7
// baseline (479.115 us; speedup 1.0000x reference)
//
#include <hip/hip_runtime.h>
#include <math.h>

#define NBATCH 4
#define NSEQ   1024
#define DHID   512
#define NHEADS 16
#define ROWS   (NBATCH*NSEQ)   /* 4096  */
#define VROWS  (ROWS*3)        /* 12288 */
#define ATT_FACTOR 0.08838834764831845f  /* 0.5/sqrt(32) */
#define LOG2E 1.4426950408889634f
#define F2 (ATT_FACTOR*LOG2E)
#define SM_SHIFT (16.0f*LOG2E)   /* fixed softmax shift: logits bounded << 16 */

typedef __attribute__((ext_vector_type(8))) short short8;   // 8 bf16 = 4 VGPR
typedef __attribute__((ext_vector_type(4))) float floatx4;  // MFMA C/D frag

#define AS1 __attribute__((address_space(1)))
#define AS3 __attribute__((address_space(3)))
#define GLOAD_LDS16(g, l) \
  __builtin_amdgcn_global_load_lds((const AS1 void*)(g), (AS3 void*)(l), 16, 0, 0)

__device__ __forceinline__ ushort f2bf(float x) {
  union { float f; unsigned u; } v; v.f = x;
  unsigned r = v.u + 0x7fff + ((v.u >> 16) & 1);   // round-to-nearest-even
  return (ushort)(r >> 16);
}
__device__ __forceinline__ float bf2f(ushort u) {
  union { unsigned u; float f; } v; v.u = ((unsigned)u) << 16; return v.f;
}

// ---------------- LayerNorm: one block per row of 512 ----------------
template<int OBF>
__global__ __launch_bounds__(256) void ln_kernel(
    const float* __restrict__ x, void* __restrict__ y, int ystride,
    const float* __restrict__ g, const float* __restrict__ beta)
{
  int row = blockIdx.x;
  int t = threadIdx.x;
  const float* xr = x + (size_t)row * DHID;
  float2 v = ((const float2*)xr)[t];
  float s  = v.x + v.y;
  float ss = v.x*v.x + v.y*v.y;
  #pragma unroll
  for (int off = 32; off > 0; off >>= 1) {
    s  += __shfl_down(s, off);
    ss += __shfl_down(ss, off);
  }
  __shared__ float red[8];
  int w = t >> 6;
  if ((t & 63) == 0) { red[w*2] = s; red[w*2+1] = ss; }
  __syncthreads();
  s  = red[0] + red[2] + red[4] + red[6];
  ss = red[1] + red[3] + red[5] + red[7];
  float mean = s * (1.0f/DHID);
  float var  = ss * (1.0f/DHID) - mean*mean;
  float rstd = rsqrtf(var + 1e-5f);
  float2 gg = ((const float2*)g)[t];
  float2 bb = ((const float2*)beta)[t];
  float2 o;
  o.x = (v.x - mean) * rstd * gg.x + bb.x;
  o.y = (v.y - mean) * rstd * gg.y + bb.y;
  if constexpr (OBF) {
    ushort2 u = { f2bf(o.x), f2bf(o.y) };
    *(ushort2*)&((ushort*)y)[(size_t)row * ystride + 2*t] = u;
  } else {
    *(float2*)&((float*)y)[(size_t)row * ystride + 2*t] = o;
  }
}

// ---- batched weight transpose: fp32 [K][N] -> bf16 [N][K], 64x64 tiles ----
struct WJobs {
  const float* src[9];
  ushort*      dst[9];
  int K[9];
  int N[9];
  int blk0[10];
};

__global__ __launch_bounds__(256) void wtrans_all_kernel(WJobs J)
{
  __shared__ float Ts[64][65];
  int bid = blockIdx.x;
  int j = 0;
  #pragma unroll
  for (int i = 1; i < 9; i++) if (bid >= J.blk0[i]) j = i;
  const float* W = J.src[j];
  ushort* Wt = J.dst[j];
  int K = J.K[j], N = J.N[j];
  int local = bid - J.blk0[j];
  int nx = N >> 6;
  int bx = local - (local / nx) * nx;
  int by = local / nx;
  int k0 = by*64, n0 = bx*64;
  int t = threadIdx.x;
  #pragma unroll
  for (int p = 0; p < 4; p++) {
    int f = p*256 + t;
    int r = f >> 4, c = (f & 15)*4;
    float4 v = *(const float4*)&W[(size_t)(k0+r)*N + n0 + c];
    Ts[r][c] = v.x; Ts[r][c+1] = v.y; Ts[r][c+2] = v.z; Ts[r][c+3] = v.w;
  }
  __syncthreads();
  #pragma unroll
  for (int p = 0; p < 2; p++) {
    int gidx = p*256 + t;
    int nr = gidx >> 3, kc = (gidx & 7)*8;
    ushort u[8];
    #pragma unroll
    for (int x = 0; x < 8; x++) u[x] = f2bf(Ts[kc+x][nr]);
    ushort4 a = {u[0],u[1],u[2],u[3]}, b4 = {u[4],u[5],u[6],u[7]};
    *(ushort4*)&Wt[(size_t)(n0+nr)*K + k0 + kc]     = a;
    *(ushort4*)&Wt[(size_t)(n0+nr)*K + k0 + kc + 4] = b4;
  }
}

// ---- flat fp32 -> bf16 convert (4 elements/thread) ----
__global__ __launch_bounds__(256) void conv_bf16_kernel(
    const float* __restrict__ x, ushort* __restrict__ y)
{
  int i = blockIdx.x*256 + threadIdx.x;
  float4 v = ((const float4*)x)[i];
  ushort4 u = { f2bf(v.x), f2bf(v.y), f2bf(v.z), f2bf(v.w) };
  ((ushort4*)y)[i] = u;
}

// ---- concat bq|bk|bv -> Bqkv[4608] ----
__global__ __launch_bounds__(256) void biascat_kernel(
    const float* __restrict__ bq, const float* __restrict__ bk,
    const float* __restrict__ bv, float* __restrict__ o)
{
  int i = blockIdx.x*256 + threadIdx.x;   // < 4608
  float v = (i < 2048) ? bq[i] : (i < 4096 ? bk[i-2048] : bv[i-4096]);
  o[i] = v;
}

// ------------- bf16 MFMA GEMM: C = act(A@W + bias) + resid -------------
template<int ACT, int HAS_BIAS, int HAS_RES, int OUT_BF16, int DUAL>
__global__ __launch_bounds__(256) void gemm_mfma_kernel(
    const ushort* __restrict__ A, const ushort* __restrict__ Bt,
    const float* __restrict__ bias, const float* __restrict__ resid,
    void* __restrict__ Cv, ushort* __restrict__ C2,
    int M, int N, int K)
{
  __shared__ ushort As[2][128*32];   // [m][k] 8 KB per buf
  __shared__ ushort Bs[2][128*32];   // [n][k] 8 KB per buf
  int t = threadIdx.x;
  int w = t >> 6, lane = t & 63;
  int q16 = lane & 15, quad = lane >> 4;
  int m0 = blockIdx.y * 128, n0 = blockIdx.x * 128;
  int wm = (w & 1) * 64, wn = (w >> 1) * 64;

  int r0 = t >> 2;            // 0..63
  int c0 = (t & 3) * 8;       // 0,8,16,24
  const ushort* Ag = A  + (size_t)(m0 + r0) * K + c0;
  const ushort* Bg = Bt + (size_t)(n0 + r0) * K + c0;
  int wb = w * 512;           // ushort offset

  floatx4 acc[4][4];
  #pragma unroll
  for (int i = 0; i < 4; i++)
    #pragma unroll
    for (int j = 0; j < 4; j++) acc[i][j] = (floatx4){0.f,0.f,0.f,0.f};

  #define STAGE(buf, kk) do { \
    GLOAD_LDS16(Ag + (kk),                 &As[buf][wb]); \
    GLOAD_LDS16(Ag + (size_t)64*K + (kk),  &As[buf][2048 + wb]); \
    GLOAD_LDS16(Bg + (kk),                 &Bs[buf][wb]); \
    GLOAD_LDS16(Bg + (size_t)64*K + (kk),  &Bs[buf][2048 + wb]); \
  } while (0)

  STAGE(0, 0);
  __syncthreads();

  int nt = K >> 5;
  int cur = 0;
  for (int kt = 0; kt < nt; kt++) {
    if (kt + 1 < nt) STAGE(cur ^ 1, (kt + 1) * 32);
    short8 af[4], bf4[4];
    #pragma unroll
    for (int i = 0; i < 4; i++) {
      af[i]  = *(const short8*)&As[cur][(wm + i*16 + q16)*32 + quad*8];
      bf4[i] = *(const short8*)&Bs[cur][(wn + i*16 + q16)*32 + quad*8];
    }
    #pragma unroll
    for (int i = 0; i < 4; i++)
      #pragma unroll
      for (int j = 0; j < 4; j++)
        acc[i][j] = __builtin_amdgcn_mfma_f32_16x16x32_bf16(af[i], bf4[j], acc[i][j], 0, 0, 0);
    __syncthreads();
    cur ^= 1;
  }
  #undef STAGE

  float* Cf = (float*)Cv;
  ushort* Cu = (ushort*)Cv;
  float bj[4];
  #pragma unroll
  for (int j = 0; j < 4; j++)
    bj[j] = HAS_BIAS ? bias[n0 + wn + j*16 + q16] : 0.f;
  #pragma unroll
  for (int i = 0; i < 4; i++) {
    #pragma unroll
    for (int r = 0; r < 4; r++) {
      int row = m0 + wm + i*16 + quad*4 + r;
      size_t base = (size_t)row * N;
      #pragma unroll
      for (int j = 0; j < 4; j++) {
        int col = n0 + wn + j*16 + q16;
        float v = acc[i][j][r] + bj[j];
        if constexpr (ACT == 1) v = v / (1.f + __expf(-v));
        if constexpr (HAS_RES) v += resid[base + col];
        if constexpr (OUT_BF16) Cu[base + col] = f2bf(v);
        else                    Cf[base + col] = v;
        if constexpr (DUAL) C2[base + col] = f2bf(v);
      }
    }
  }
}

// ---- merged Wo/Wvo GEMM: A = HRES||VRES [16384][512] bf16, K=N=512 ----
// rows < 4096: Hout = A@WoT + bo + H;  rows >= 4096: Vout = A@WvoT + V (+bf16 dual)
__global__ __launch_bounds__(256) void gemm_wovo_kernel(
    const ushort* __restrict__ A,
    const ushort* __restrict__ WoTp, const ushort* __restrict__ WvoTp,
    const float* __restrict__ bo,
    const float* __restrict__ Hres, const float* __restrict__ Vres,
    float* __restrict__ Hout, float* __restrict__ Vout,
    ushort* __restrict__ Voutbf)
{
  const int K = 512;
  __shared__ ushort As[2][128*32];
  __shared__ ushort Bs[2][128*32];
  int t = threadIdx.x;
  int w = t >> 6, lane = t & 63;
  int q16 = lane & 15, quad = lane >> 4;
  int m0 = blockIdx.y * 128, n0 = blockIdx.x * 128;
  int wm = (w & 1) * 64, wn = (w >> 1) * 64;
  bool inH = (m0 < 4096);
  const ushort* Bt = inH ? WoTp : WvoTp;

  int r0 = t >> 2;
  int c0 = (t & 3) * 8;
  const ushort* Ag = A  + (size_t)(m0 + r0) * K + c0;
  const ushort* Bg = Bt + (size_t)(n0 + r0) * K + c0;
  int wb = w * 512;

  floatx4 acc[4][4];
  #pragma unroll
  for (int i = 0; i < 4; i++)
    #pragma unroll
    for (int j = 0; j < 4; j++) acc[i][j] = (floatx4){0.f,0.f,0.f,0.f};

  #define STAGE(buf, kk) do { \
    GLOAD_LDS16(Ag + (kk),                 &As[buf][wb]); \
    GLOAD_LDS16(Ag + (size_t)64*K + (kk),  &As[buf][2048 + wb]); \
    GLOAD_LDS16(Bg + (kk),                 &Bs[buf][wb]); \
    GLOAD_LDS16(Bg + (size_t)64*K + (kk),  &Bs[buf][2048 + wb]); \
  } while (0)

  STAGE(0, 0);
  __syncthreads();

  int cur = 0;
  for (int kt = 0; kt < 16; kt++) {
    if (kt + 1 < 16) STAGE(cur ^ 1, (kt + 1) * 32);
    short8 af[4], bf4[4];
    #pragma unroll
    for (int i = 0; i < 4; i++) {
      af[i]  = *(const short8*)&As[cur][(wm + i*16 + q16)*32 + quad*8];
      bf4[i] = *(const short8*)&Bs[cur][(wn + i*16 + q16)*32 + quad*8];
    }
    #pragma unroll
    for (int i = 0; i < 4; i++)
      #pragma unroll
      for (int j = 0; j < 4; j++)
        acc[i][j] = __builtin_amdgcn_mfma_f32_16x16x32_bf16(af[i], bf4[j], acc[i][j], 0, 0, 0);
    __syncthreads();
    cur ^= 1;
  }
  #undef STAGE

  float bj[4];
  #pragma unroll
  for (int j = 0; j < 4; j++)
    bj[j] = inH ? bo[n0 + wn + j*16 + q16] : 0.f;
  #pragma unroll
  for (int i = 0; i < 4; i++) {
    #pragma unroll
    for (int r = 0; r < 4; r++) {
      int row = m0 + wm + i*16 + quad*4 + r;
      #pragma unroll
      for (int j = 0; j < 4; j++) {
        int col = n0 + wn + j*16 + q16;
        float v = acc[i][j][r] + bj[j];
        if (inH) {
          size_t idx = (size_t)row * 512 + col;
          Hout[idx] = v + Hres[idx];
        } else {
          size_t idx = (size_t)(row - 4096) * 512 + col;
          float vv = v + Vres[idx];
          Vout[idx] = vv;
          Voutbf[idx] = f2bf(vv);
        }
      }
    }
  }
}

// ---- W2 GEMM + fused finale: h = S1@W2T + b2f; Hout += h[:,:512];
//      Vout[row*3+c] += h[:,512+d] * VP[row*3+c][512+d]  (c=0..2) ----
__global__ __launch_bounds__(256) void gemm_w2_finale_kernel(
    const ushort* __restrict__ A, const ushort* __restrict__ Bt,
    const float* __restrict__ bias, const float* __restrict__ VP,
    float* __restrict__ Hout, float* __restrict__ Vout)
{
  const int K = 2048;
  __shared__ ushort As[2][128*32];
  __shared__ ushort Bs[2][128*32];
  int t = threadIdx.x;
  int w = t >> 6, lane = t & 63;
  int q16 = lane & 15, quad = lane >> 4;
  int m0 = blockIdx.y * 128, n0 = blockIdx.x * 128;
  int wm = (w & 1) * 64, wn = (w >> 1) * 64;

  int r0 = t >> 2;
  int c0 = (t & 3) * 8;
  const ushort* Ag = A  + (size_t)(m0 + r0) * K + c0;
  const ushort* Bg = Bt + (size_t)(n0 + r0) * K + c0;
  int wb = w * 512;

  floatx4 acc[4][4];
  #pragma unroll
  for (int i = 0; i < 4; i++)
    #pragma unroll
    for (int j = 0; j < 4; j++) acc[i][j] = (floatx4){0.f,0.f,0.f,0.f};

  #define STAGE(buf, kk) do { \
    GLOAD_LDS16(Ag + (kk),                 &As[buf][wb]); \
    GLOAD_LDS16(Ag + (size_t)64*K + (kk),  &As[buf][2048 + wb]); \
    GLOAD_LDS16(Bg + (kk),                 &Bs[buf][wb]); \
    GLOAD_LDS16(Bg + (size_t)64*K + (kk),  &Bs[buf][2048 + wb]); \
  } while (0)

  STAGE(0, 0);
  __syncthreads();

  int cur = 0;
  for (int kt = 0; kt < 64; kt++) {
    if (kt + 1 < 64) STAGE(cur ^ 1, (kt + 1) * 32);
    short8 af[4], bf4[4];
    #pragma unroll
    for (int i = 0; i < 4; i++) {
      af[i]  = *(const short8*)&As[cur][(wm + i*16 + q16)*32 + quad*8];
      bf4[i] = *(const short8*)&Bs[cur][(wn + i*16 + q16)*32 + quad*8];
    }
    #pragma unroll
    for (int i = 0; i < 4; i++)
      #pragma unroll
      for (int j = 0; j < 4; j++)
        acc[i][j] = __builtin_amdgcn_mfma_f32_16x16x32_bf16(af[i], bf4[j], acc[i][j], 0, 0, 0);
    __syncthreads();
    cur ^= 1;
  }
  #undef STAGE

  float bj[4];
  #pragma unroll
  for (int j = 0; j < 4; j++)
    bj[j] = bias[n0 + wn + j*16 + q16];
  bool inH = (n0 < 512);   // 128-col tiles never straddle col 512
  #pragma unroll
  for (int i = 0; i < 4; i++) {
    #pragma unroll
    for (int r = 0; r < 4; r++) {
      int row = m0 + wm + i*16 + quad*4 + r;
      #pragma unroll
      for (int j = 0; j < 4; j++) {
        int col = n0 + wn + j*16 + q16;
        float v = acc[i][j][r] + bj[j];
        if (inH) {
          Hout[(size_t)row * 512 + col] += v;
        } else {
          int d = col - 512;
          #pragma unroll
          for (int c = 0; c < 3; c++) {
            size_t r3 = (size_t)(row * 3 + c);
            Vout[r3 * 512 + d] += v * VP[r3 * 1024 + 512 + d];
          }
        }
      }
    }
  }
}

// --- fused bias, bf16, pre-scaled by log2e: Bc2 = mask ? (Db+Rb)*LOG2E : -1e30 ---
__global__ __launch_bounds__(256) void bias2_kernel(
    const float* __restrict__ Db, const float* __restrict__ Rb,
    const int* __restrict__ Mask, ushort* __restrict__ Bc2)
{
  int i2 = blockIdx.x*256 + threadIdx.x;    // < 2M (2 elems each)
  int e = i2 * 2;
  int b = e >> 20;
  int m = e & 1023;
  float2 d = *(const float2*)&Db[e];
  float2 r = *(const float2*)&Rb[e];
  ushort2 o;
  o.x = Mask[b*NSEQ + m]     ? f2bf((d.x + r.x)*LOG2E) : f2bf(-1e30f);
  o.y = Mask[b*NSEQ + m + 1] ? f2bf((d.y + r.y)*LOG2E) : f2bf(-1e30f);
  *(ushort2*)&Bc2[e] = o;
}

// ------- V_attn transpose -> bf16 Vt[b][h][d(128)][n(1024)] -------
__global__ __launch_bounds__(256) void vtrans_kernel(
    const ushort* __restrict__ QKV, const ushort* __restrict__ VVr,
    ushort* __restrict__ Vt)
{
  __shared__ float Ts[64][33];
  int t = threadIdx.x;
  int bh = blockIdx.z;          // b*16+h
  int b = bh >> 4, h = bh & 15;
  int dt = blockIdx.y;          // 0..3 -> d0
  int nt = blockIdx.x;          // 0..15 -> n0
  int d0 = dt*32, n0 = nt*64;
  #pragma unroll
  for (int i = 0; i < 2; i++) {
    int nl = (t >> 3) + i*32;
    int c4 = (t & 7)*4;
    const ushort* src;
    if (dt == 0) src = &QKV[(size_t)(b*NSEQ + n0 + nl)*4608 + 4096 + h*32 + c4];
    else { int c = dt - 1; src = &VVr[((size_t)(b*NSEQ + n0 + nl)*3 + c)*512 + h*32 + c4]; }
    ushort4 v = *(const ushort4*)src;
    Ts[nl][c4] = bf2f(v.x); Ts[nl][c4+1] = bf2f(v.y);
    Ts[nl][c4+2] = bf2f(v.z); Ts[nl][c4+3] = bf2f(v.w);
  }
  __syncthreads();
  int dl = t >> 3;              // 0..31
  int n8 = (t & 7)*8;
  ushort u[8];
  #pragma unroll
  for (int k = 0; k < 8; k++) u[k] = f2bf(Ts[n8+k][dl]);
  size_t ob = ((size_t)bh*128 + d0 + dl)*NSEQ + n0 + n8;
  ushort4 u0 = {u[0],u[1],u[2],u[3]}, u1 = {u[4],u[5],u[6],u[7]};
  *(ushort4*)&Vt[ob]     = u0;
  *(ushort4*)&Vt[ob + 4] = u1;
}

// ------------- bf16 MFMA flash attention v4 (reverted from v5) -----------
// Swapped QK^T (mfma(K,Q) -> S^T): lane holds one q-row x 4 contiguous keys;
// bias reads b64 vector, P via v_cvt_pk_bf16_f32, P stores b64 vector;
// PV via 16x16x32 MFMA through the Ps LDS round-trip (full-rate).
__global__ __launch_bounds__(256, 2) void attn_mfma_kernel(
    const ushort* __restrict__ QKV,
    const ushort* __restrict__ Vt, const ushort* __restrict__ Bc2,
    ushort* __restrict__ HRES, ushort* __restrict__ VRES)
{
  __shared__ union {
    ushort q[128][136];                  // Q staging (transient) 34816 B
    struct {
      ushort k[64][136];                 // 17408 B  K tile [key][d]
      ushort v[128][72];                 // 18432 B  V tile [d][key]
      ushort bias[128][72];              // 18432 B  bias tile [qrow][key]
    } s;                                 // 54272 B
  } S;
  __shared__ ushort Ps[4][32][72];       // per-wave P (bf16) 18432 B

  int t = threadIdx.x;
  int w = t >> 6, lane = t & 63;
  int q16 = lane & 15, quad = lane >> 4;
  int h = blockIdx.x, qt = blockIdx.y, b = blockIdx.z;
  int q0 = qt * 128;

  // prefetch registers for one 64-key tile (K 16KB, V 16KB, bias 16KB)
  float4 rk0, rk1, rk2, rk3;
  float4 rv0, rv1, rv2, rv3;
  float4 rb0, rb1, rb2, rb3;
  const size_t kbase = (size_t)(b*NSEQ)*4608 + 2048 + h*128 + (t&3)*8;
  const size_t vbase = ((size_t)(b*NHEADS + h)*128 + (t>>3))*NSEQ + (t&7)*8;
  const size_t bbase = (size_t)(b*NSEQ + q0 + (t>>3))*NSEQ + (t&7)*8;
  int kr = t >> 2;   // K row this thread stages
  int kc = (t & 3)*8;
  int vr = t >> 3, vc = (t & 7)*8;

  #define LOADT(m0_) do { \
    const ushort* kp = &QKV[kbase + (size_t)((m0_) + kr)*4608]; \
    rk0 = *(const float4*)(kp +  0); \
    rk1 = *(const float4*)(kp + 32); \
    rk2 = *(const float4*)(kp + 64); \
    rk3 = *(const float4*)(kp + 96); \
    const ushort* vp = &Vt[vbase + (m0_)]; \
    rv0 = *(const float4*)(vp + (size_t) 0*NSEQ); \
    rv1 = *(const float4*)(vp + (size_t)32*NSEQ); \
    rv2 = *(const float4*)(vp + (size_t)64*NSEQ); \
    rv3 = *(const float4*)(vp + (size_t)96*NSEQ); \
    const ushort* bp2 = &Bc2[bbase + (m0_)]; \
    rb0 = *(const float4*)(bp2 + (size_t) 0*NSEQ); \
    rb1 = *(const float4*)(bp2 + (size_t)32*NSEQ); \
    rb2 = *(const float4*)(bp2 + (size_t)64*NSEQ); \
    rb3 = *(const float4*)(bp2 + (size_t)96*NSEQ); \
  } while (0)

  #define STORET() do { \
    *(float4*)&S.s.k[kr][kc +  0] = rk0; \
    *(float4*)&S.s.k[kr][kc + 32] = rk1; \
    *(float4*)&S.s.k[kr][kc + 64] = rk2; \
    *(float4*)&S.s.k[kr][kc + 96] = rk3; \
    *(float4*)&S.s.v[vr +  0][vc] = rv0; \
    *(float4*)&S.s.v[vr + 32][vc] = rv1; \
    *(float4*)&S.s.v[vr + 64][vc] = rv2; \
    *(float4*)&S.s.v[vr + 96][vc] = rv3; \
    *(float4*)&S.s.bias[vr +  0][vc] = rb0; \
    *(float4*)&S.s.bias[vr + 32][vc] = rb1; \
    *(float4*)&S.s.bias[vr + 64][vc] = rb2; \
    *(float4*)&S.s.bias[vr + 96][vc] = rb3; \
  } while (0)

  LOADT(0);   // tile-0 loads fly while we stage Q

  // ---- stage Q tile 128x128 bf16 ----
  #pragma unroll
  for (int i = 0; i < 8; i++) {
    int f = t + i*256;
    int r = f >> 4, c8 = f & 15;
    *(float4*)&S.q[r][c8*8] =
        *(const float4*)&QKV[(size_t)(b*NSEQ + q0 + r)*4608 + h*128 + c8*8];
  }
  __syncthreads();
  short8 qf[2][4];
  #pragma unroll
  for (int rg = 0; rg < 2; rg++)
    #pragma unroll
    for (int c = 0; c < 4; c++)
      qf[rg][c] = *(const short8*)&S.q[w*32 + rg*16 + q16][c*32 + quad*8];

  floatx4 o[2][8];
  #pragma unroll
  for (int rg = 0; rg < 2; rg++)
    #pragma unroll
    for (int i = 0; i < 8; i++) o[rg][i] = (floatx4){0.f,0.f,0.f,0.f};
  float l_i[2] = {0.f, 0.f};   // per-lane partial denom for qrow q16 (rg)

  #pragma unroll 1
  for (int it = 0; it < 16; it++) {
    __syncthreads();               // LDS free (iter0: Q frag reads done)
    STORET();
    if (it < 15) LOADT((it + 1) * 64);   // prefetch under compute
    __syncthreads();               // tile ready

    // ---- S^T = K Q^T (swapped): C[key][qrow], lane: col=q16=qrow,
    //      rows = keys g*16 + quad*4 + {0..3}
    floatx4 sf[2][4];
    #pragma unroll
    for (int rg = 0; rg < 2; rg++)
      #pragma unroll
      for (int g = 0; g < 4; g++) sf[rg][g] = (floatx4){0.f,0.f,0.f,0.f};
    __builtin_amdgcn_s_setprio(1);
    #pragma unroll
    for (int c = 0; c < 4; c++) {
      short8 kf[4];
      #pragma unroll
      for (int g = 0; g < 4; g++)
        kf[g] = *(const short8*)&S.s.k[g*16 + q16][c*32 + quad*8];
      #pragma unroll
      for (int rg = 0; rg < 2; rg++)
        #pragma unroll
        for (int g = 0; g < 4; g++)
          sf[rg][g] = __builtin_amdgcn_mfma_f32_16x16x32_bf16(kf[g], qf[rg][c], sf[rg][g], 0, 0, 0);
    }
    __builtin_amdgcn_s_setprio(0);

    // ---- fixed-shift softmax: vector bias read, packed bf16 convert,
    //      vector P store (keys contiguous per lane)
    #pragma unroll
    for (int rg = 0; rg < 2; rg++) {
      int brow = w*32 + rg*16 + q16;
      #pragma unroll
      for (int g = 0; g < 4; g++) {
        ushort4 bb = *(const ushort4*)&S.s.bias[brow][g*16 + quad*4];
        float p0 = exp2f(sf[rg][g][0]*F2 + bf2f(bb.x) - SM_SHIFT);
        float p1 = exp2f(sf[rg][g][1]*F2 + bf2f(bb.y) - SM_SHIFT);
        float p2 = exp2f(sf[rg][g][2]*F2 + bf2f(bb.z) - SM_SHIFT);
        float p3 = exp2f(sf[rg][g][3]*F2 + bf2f(bb.w) - SM_SHIFT);
        l_i[rg] += (p0 + p1) + (p2 + p3);
        unsigned d0, d1;
        asm("v_cvt_pk_bf16_f32 %0, %1, %2" : "=v"(d0) : "v"(p0), "v"(p1));
        asm("v_cvt_pk_bf16_f32 %0, %1, %2" : "=v"(d1) : "v"(p2), "v"(p3));
        uint2 dd = { d0, d1 };
        *(uint2*)&Ps[w][rg*16 + q16][g*16 + quad*4] = dd;
      }
    }

    // ---- P(32x64) @ V(64x128): wave-synchronous LDS round-trip ----
    short8 pf[2][2];
    #pragma unroll
    for (int rg = 0; rg < 2; rg++)
      #pragma unroll
      for (int ks = 0; ks < 2; ks++)
        pf[rg][ks] = *(const short8*)&Ps[w][rg*16 + q16][ks*32 + quad*8];
    __builtin_amdgcn_s_setprio(1);
    #pragma unroll
    for (int tt = 0; tt < 8; tt++) {
      short8 vf0 = *(const short8*)&S.s.v[tt*16 + q16][quad*8];
      short8 vf1 = *(const short8*)&S.s.v[tt*16 + q16][32 + quad*8];
      #pragma unroll
      for (int rg = 0; rg < 2; rg++) {
        o[rg][tt] = __builtin_amdgcn_mfma_f32_16x16x32_bf16(pf[rg][0], vf0, o[rg][tt], 0, 0, 0);
        o[rg][tt] = __builtin_amdgcn_mfma_f32_16x16x32_bf16(pf[rg][1], vf1, o[rg][tt], 0, 0, 0);
      }
    }
    __builtin_amdgcn_s_setprio(0);
  }
  #undef LOADT
  #undef STORET

  // ---- epilogue: reduce l across quads, redistribute per output row ----
  #pragma unroll
  for (int rg = 0; rg < 2; rg++) {
    float l = l_i[rg];
    l += __shfl_xor(l, 16);
    l += __shfl_xor(l, 32);        // lanes with q16=r hold row-r full sum
    #pragma unroll
    for (int i = 0; i < 4; i++) {
      float li = __shfl(l, quad*4 + i);   // denom for output row quad*4+i
      float inv = 1.0f / li;
      int grow = b*NSEQ + q0 + w*32 + rg*16 + quad*4 + i;
      #pragma unroll
      for (int tt = 0; tt < 2; tt++)
        HRES[(size_t)grow*512 + h*32 + tt*16 + q16] = f2bf(o[rg][tt][i] * inv);
      #pragma unroll
      for (int tt = 2; tt < 8; tt++) {
        int c = (tt - 2) >> 1;
        int jj = ((tt - 2) & 1)*16 + q16;
        VRES[((size_t)grow*3 + c)*512 + h*32 + jj] = f2bf(o[rg][tt][i] * inv);
      }
    }
  }
}

// ------------- scaler second half: ||V1||_2, bf16 out -------------
__global__ __launch_bounds__(256) void vnorm_kernel(
    const float* __restrict__ VP, ushort* __restrict__ SC)
{
  int idx = blockIdx.x*256 + threadIdx.x;   // < ROWS*512
  int row = idx >> 9;
  int d = idx & 511;
  const float* p = VP + (size_t)row*3072 + d;
  float a = p[0], b = p[1024], c = p[2048];
  SC[(size_t)row*1024 + 512 + d] = f2bf(sqrtf(a*a + b*b + c*c));
}

extern "C" void kernel_launch(void* const* d_in, const int* in_sizes, int n_in,
                              void* d_out, int out_size, void* d_ws, size_t ws_size,
                              hipStream_t stream)
{
  const float* H    = (const float*)d_in[0];
  const float* V    = (const float*)d_in[1];
  const float* Db   = (const float*)d_in[2];
  const float* Rb   = (const float*)d_in[3];
  const int*   Mask = (const int*)d_in[4];
  const float* g1   = (const float*)d_in[5];
  const float* be1  = (const float*)d_in[6];
  const float* Wq   = (const float*)d_in[7];
  const float* bq   = (const float*)d_in[8];
  const float* Wk   = (const float*)d_in[9];
  const float* bkk  = (const float*)d_in[10];
  const float* Wv   = (const float*)d_in[11];
  const float* bv   = (const float*)d_in[12];
  const float* Wvv  = (const float*)d_in[13];
  const float* Wo   = (const float*)d_in[14];
  const float* bo   = (const float*)d_in[15];
  const float* Wvo  = (const float*)d_in[16];
  const float* g2   = (const float*)d_in[17];
  const float* be2  = (const float*)d_in[18];
  const float* Wlv  = (const float*)d_in[19];
  const float* W1   = (const float*)d_in[20];
  const float* b1f  = (const float*)d_in[21];
  const float* W2   = (const float*)d_in[22];
  const float* b2f  = (const float*)d_in[23];

  float* Hout = (float*)d_out;                  // 4096 x 512
  float* Vout = Hout + (size_t)ROWS*DHID;       // 12288 x 512

  char* w = (char*)d_ws;
  const size_t MB = 1024*1024;
  const size_t KB = 1024;
  // weights bf16 transposed (live whole launch): [0, 15.36 MB)
  ushort* WqT  = (ushort*)(w + 0);
  ushort* WkT  = (ushort*)(w + 2048*KB);
  ushort* WvT  = (ushort*)(w + 4096*KB);
  ushort* WvvT = (ushort*)(w + 4608*KB);
  ushort* WoT  = (ushort*)(w + 5120*KB);
  ushort* WvoT = (ushort*)(w + 5632*KB);
  ushort* WlvT = (ushort*)(w + 6144*KB);
  ushort* W1T  = (ushort*)(w + 7168*KB);
  ushort* W2T  = (ushort*)(w + 11264*KB);
  float*  Bqkv = (float*)(w + 15360*KB);  // 18 KB concat bias
  // phase 1
  ushort* HNbf  = (ushort*)(w + 16*MB);   //  4MB
  ushort* QKVbf = (ushort*)(w + 20*MB);   // 36MB [4096][4608]
  ushort* VVrbf = (ushort*)(w + 56*MB);   // 12MB
  ushort* Vbf   = (ushort*)(w + 68*MB);   // 12MB
  ushort* Vtb   = (ushort*)(w + 80*MB);   // 16MB
  ushort* Bc2   = (ushort*)(w + 96*MB);   //  8MB  bf16 bias*log2e
  ushort* HRESbf = (ushort*)(w + 104*MB); //  4MB
  ushort* VRESbf = (ushort*)(w + 108*MB); // 12MB  (phase-1 peak 120 MB)
  // phase 2 (aliases dead phase-1 regions)
  ushort* Voutbf = (ushort*)(w + 20*MB);  // 12MB (QKV dead after attn)
  float*  VP     = (float*)(w + 56*MB);   // 48MB (VVr/Vbf/Vtb/Bc2 dead)
  ushort* SCbf   = (ushort*)(w + 104*MB); //  8MB
  ushort* S1bf   = (ushort*)(w + 112*MB); // 16MB (peak 128 MB)

  dim3 blk(256);

  // ---- weight prep: one batched launch ----
  WJobs J;
  const float* ws_[9] = {Wq, Wk, Wv, Wvv, Wo, Wvo, Wlv, W1, W2};
  ushort* wd_[9] = {WqT, WkT, WvT, WvvT, WoT, WvoT, WlvT, W1T, W2T};
  int wk_[9] = {512, 512, 512, 512, 512, 512, 512, 1024, 2048};
  int wn_[9] = {2048, 2048, 512, 512, 512, 512, 1024, 2048, 1024};
  int off = 0;
  for (int i = 0; i < 9; i++) {
    J.src[i] = ws_[i]; J.dst[i] = wd_[i]; J.K[i] = wk_[i]; J.N[i] = wn_[i];
    J.blk0[i] = off;
    off += (wn_[i] >> 6) * (wk_[i] >> 6);
  }
  J.blk0[9] = off;   // 1920
  wtrans_all_kernel<<<off, blk, 0, stream>>>(J);

  ln_kernel<1><<<ROWS, blk, 0, stream>>>(H, HNbf, DHID, g1, be1);
  conv_bf16_kernel<<<(VROWS*DHID/4)/256, blk, 0, stream>>>(V, Vbf);
  biascat_kernel<<<18, blk, 0, stream>>>(bq, bkk, bv, Bqkv);

  // fused Q|K|V GEMM: [4096,512] @ [512,4608] -> bf16 [4096][4608]
  gemm_mfma_kernel<0,1,0,1,0><<<dim3(36, 32), blk, 0, stream>>>(HNbf, WqT, Bqkv, nullptr, QKVbf, nullptr, 4096, 4608, 512);
  gemm_mfma_kernel<0,0,0,1,0><<<dim3( 4, 96), blk, 0, stream>>>(Vbf, WvvT, nullptr, nullptr, VVrbf, nullptr, 12288, 512, 512);

  bias2_kernel<<<(NBATCH*NSEQ*NSEQ/2)/256, blk, 0, stream>>>(Db, Rb, Mask, Bc2);
  vtrans_kernel<<<dim3(16, 4, 64), blk, 0, stream>>>(QKVbf, VVrbf, Vtb);

  attn_mfma_kernel<<<dim3(16, 8, 4), blk, 0, stream>>>(QKVbf, Vtb, Bc2, HRESbf, VRESbf);

  // merged Wo + Wvo (HRESbf||VRESbf contiguous [16384][512])
  gemm_wovo_kernel<<<dim3(4, 128), blk, 0, stream>>>(HRESbf, WoT, WvoT, bo, H, V, Hout, Vout, Voutbf);

  ln_kernel<1><<<ROWS, blk, 0, stream>>>(Hout, SCbf, 1024, g2, be2);
  gemm_mfma_kernel<0,0,0,0,0><<<dim3(8, 96), blk, 0, stream>>>(Voutbf, WlvT, nullptr, nullptr, VP, nullptr, 12288, 1024, 512);
  vnorm_kernel<<<(ROWS*DHID)/256, blk, 0, stream>>>(VP, SCbf);

  gemm_mfma_kernel<1,1,0,1,0><<<dim3(16, 32), blk, 0, stream>>>(SCbf, W1T, b1f, nullptr, S1bf, nullptr, 4096, 2048, 1024);
  // W2 GEMM with fused finale (replaces HHb write + finale kernel)
  gemm_w2_finale_kernel<<<dim3(8, 32), blk, 0, stream>>>(S1bf, W2T, b2f, VP, Hout, Vout);
}

// Round 8
// 467.990 us; speedup vs baseline: 1.0238x; 1.0238x over previous
//
#include <hip/hip_runtime.h>
#include <math.h>

#define NBATCH 4
#define NSEQ   1024
#define DHID   512
#define NHEADS 16
#define ROWS   (NBATCH*NSEQ)   /* 4096  */
#define VROWS  (ROWS*3)        /* 12288 */
#define ATT_FACTOR 0.08838834764831845f  /* 0.5/sqrt(32) */
#define LOG2E 1.4426950408889634f
#define F2 (ATT_FACTOR*LOG2E)
#define SM_SHIFT (16.0f*LOG2E)   /* fixed softmax shift: logits bounded << 16 */

typedef __attribute__((ext_vector_type(8))) short short8;   // 8 bf16 = 4 VGPR
typedef __attribute__((ext_vector_type(4))) float floatx4;  // MFMA C/D frag

#define AS1 __attribute__((address_space(1)))
#define AS3 __attribute__((address_space(3)))
#define GLOAD_LDS16(g, l) \
  __builtin_amdgcn_global_load_lds((const AS1 void*)(g), (AS3 void*)(l), 16, 0, 0)

__device__ __forceinline__ ushort f2bf(float x) {
  union { float f; unsigned u; } v; v.f = x;
  unsigned r = v.u + 0x7fff + ((v.u >> 16) & 1);   // round-to-nearest-even
  return (ushort)(r >> 16);
}
__device__ __forceinline__ float bf2f(ushort u) {
  union { unsigned u; float f; } v; v.u = ((unsigned)u) << 16; return v.f;
}

// ---------------- LayerNorm: one block per row of 512 ----------------
template<int OBF>
__global__ __launch_bounds__(256) void ln_kernel(
    const float* __restrict__ x, void* __restrict__ y, int ystride,
    const float* __restrict__ g, const float* __restrict__ beta)
{
  int row = blockIdx.x;
  int t = threadIdx.x;
  const float* xr = x + (size_t)row * DHID;
  float2 v = ((const float2*)xr)[t];
  float s  = v.x + v.y;
  float ss = v.x*v.x + v.y*v.y;
  #pragma unroll
  for (int off = 32; off > 0; off >>= 1) {
    s  += __shfl_down(s, off);
    ss += __shfl_down(ss, off);
  }
  __shared__ float red[8];
  int w = t >> 6;
  if ((t & 63) == 0) { red[w*2] = s; red[w*2+1] = ss; }
  __syncthreads();
  s  = red[0] + red[2] + red[4] + red[6];
  ss = red[1] + red[3] + red[5] + red[7];
  float mean = s * (1.0f/DHID);
  float var  = ss * (1.0f/DHID) - mean*mean;
  float rstd = rsqrtf(var + 1e-5f);
  float2 gg = ((const float2*)g)[t];
  float2 bb = ((const float2*)beta)[t];
  float2 o;
  o.x = (v.x - mean) * rstd * gg.x + bb.x;
  o.y = (v.y - mean) * rstd * gg.y + bb.y;
  if constexpr (OBF) {
    ushort2 u = { f2bf(o.x), f2bf(o.y) };
    *(ushort2*)&((ushort*)y)[(size_t)row * ystride + 2*t] = u;
  } else {
    *(float2*)&((float*)y)[(size_t)row * ystride + 2*t] = o;
  }
}

// ---- batched weight transpose: fp32 [K][N] -> bf16 [N][K], 64x64 tiles ----
struct WJobs {
  const float* src[9];
  ushort*      dst[9];
  int K[9];
  int N[9];
  int blk0[10];
};

__global__ __launch_bounds__(256) void wtrans_all_kernel(WJobs J)
{
  __shared__ float Ts[64][65];
  int bid = blockIdx.x;
  int j = 0;
  #pragma unroll
  for (int i = 1; i < 9; i++) if (bid >= J.blk0[i]) j = i;
  const float* W = J.src[j];
  ushort* Wt = J.dst[j];
  int K = J.K[j], N = J.N[j];
  int local = bid - J.blk0[j];
  int nx = N >> 6;
  int bx = local - (local / nx) * nx;
  int by = local / nx;
  int k0 = by*64, n0 = bx*64;
  int t = threadIdx.x;
  #pragma unroll
  for (int p = 0; p < 4; p++) {
    int f = p*256 + t;
    int r = f >> 4, c = (f & 15)*4;
    float4 v = *(const float4*)&W[(size_t)(k0+r)*N + n0 + c];
    Ts[r][c] = v.x; Ts[r][c+1] = v.y; Ts[r][c+2] = v.z; Ts[r][c+3] = v.w;
  }
  __syncthreads();
  #pragma unroll
  for (int p = 0; p < 2; p++) {
    int gidx = p*256 + t;
    int nr = gidx >> 3, kc = (gidx & 7)*8;
    ushort u[8];
    #pragma unroll
    for (int x = 0; x < 8; x++) u[x] = f2bf(Ts[kc+x][nr]);
    ushort4 a = {u[0],u[1],u[2],u[3]}, b4 = {u[4],u[5],u[6],u[7]};
    *(ushort4*)&Wt[(size_t)(n0+nr)*K + k0 + kc]     = a;
    *(ushort4*)&Wt[(size_t)(n0+nr)*K + k0 + kc + 4] = b4;
  }
}

// ---- flat fp32 -> bf16 convert (4 elements/thread) ----
__global__ __launch_bounds__(256) void conv_bf16_kernel(
    const float* __restrict__ x, ushort* __restrict__ y)
{
  int i = blockIdx.x*256 + threadIdx.x;
  float4 v = ((const float4*)x)[i];
  ushort4 u = { f2bf(v.x), f2bf(v.y), f2bf(v.z), f2bf(v.w) };
  ((ushort4*)y)[i] = u;
}

// ---- concat bq|bk|bv -> Bqkv[4608] ----
__global__ __launch_bounds__(256) void biascat_kernel(
    const float* __restrict__ bq, const float* __restrict__ bk,
    const float* __restrict__ bv, float* __restrict__ o)
{
  int i = blockIdx.x*256 + threadIdx.x;   // < 4608
  float v = (i < 2048) ? bq[i] : (i < 4096 ? bk[i-2048] : bv[i-4096]);
  o[i] = v;
}

// ------------- bf16 MFMA GEMM: C = act(A@W + bias) + resid -------------
template<int ACT, int HAS_BIAS, int HAS_RES, int OUT_BF16, int DUAL>
__global__ __launch_bounds__(256) void gemm_mfma_kernel(
    const ushort* __restrict__ A, const ushort* __restrict__ Bt,
    const float* __restrict__ bias, const float* __restrict__ resid,
    void* __restrict__ Cv, ushort* __restrict__ C2,
    int M, int N, int K)
{
  __shared__ ushort As[2][128*32];   // [m][k] 8 KB per buf
  __shared__ ushort Bs[2][128*32];   // [n][k] 8 KB per buf
  int t = threadIdx.x;
  int w = t >> 6, lane = t & 63;
  int q16 = lane & 15, quad = lane >> 4;
  int m0 = blockIdx.y * 128, n0 = blockIdx.x * 128;
  int wm = (w & 1) * 64, wn = (w >> 1) * 64;

  int r0 = t >> 2;            // 0..63
  int c0 = (t & 3) * 8;       // 0,8,16,24
  const ushort* Ag = A  + (size_t)(m0 + r0) * K + c0;
  const ushort* Bg = Bt + (size_t)(n0 + r0) * K + c0;
  int wb = w * 512;           // ushort offset

  floatx4 acc[4][4];
  #pragma unroll
  for (int i = 0; i < 4; i++)
    #pragma unroll
    for (int j = 0; j < 4; j++) acc[i][j] = (floatx4){0.f,0.f,0.f,0.f};

  #define STAGE(buf, kk) do { \
    GLOAD_LDS16(Ag + (kk),                 &As[buf][wb]); \
    GLOAD_LDS16(Ag + (size_t)64*K + (kk),  &As[buf][2048 + wb]); \
    GLOAD_LDS16(Bg + (kk),                 &Bs[buf][wb]); \
    GLOAD_LDS16(Bg + (size_t)64*K + (kk),  &Bs[buf][2048 + wb]); \
  } while (0)

  STAGE(0, 0);
  __syncthreads();

  int nt = K >> 5;
  int cur = 0;
  for (int kt = 0; kt < nt; kt++) {
    if (kt + 1 < nt) STAGE(cur ^ 1, (kt + 1) * 32);
    short8 af[4], bf4[4];
    #pragma unroll
    for (int i = 0; i < 4; i++) {
      af[i]  = *(const short8*)&As[cur][(wm + i*16 + q16)*32 + quad*8];
      bf4[i] = *(const short8*)&Bs[cur][(wn + i*16 + q16)*32 + quad*8];
    }
    #pragma unroll
    for (int i = 0; i < 4; i++)
      #pragma unroll
      for (int j = 0; j < 4; j++)
        acc[i][j] = __builtin_amdgcn_mfma_f32_16x16x32_bf16(af[i], bf4[j], acc[i][j], 0, 0, 0);
    __syncthreads();
    cur ^= 1;
  }
  #undef STAGE

  float* Cf = (float*)Cv;
  ushort* Cu = (ushort*)Cv;
  float bj[4];
  #pragma unroll
  for (int j = 0; j < 4; j++)
    bj[j] = HAS_BIAS ? bias[n0 + wn + j*16 + q16] : 0.f;
  #pragma unroll
  for (int i = 0; i < 4; i++) {
    #pragma unroll
    for (int r = 0; r < 4; r++) {
      int row = m0 + wm + i*16 + quad*4 + r;
      size_t base = (size_t)row * N;
      #pragma unroll
      for (int j = 0; j < 4; j++) {
        int col = n0 + wn + j*16 + q16;
        float v = acc[i][j][r] + bj[j];
        if constexpr (ACT == 1) v = v / (1.f + __expf(-v));
        if constexpr (HAS_RES) v += resid[base + col];
        if constexpr (OUT_BF16) Cu[base + col] = f2bf(v);
        else                    Cf[base + col] = v;
        if constexpr (DUAL) C2[base + col] = f2bf(v);
      }
    }
  }
}

// ---- merged Wo/Wvo GEMM: A = HRES||VRES [16384][512] bf16, K=N=512 ----
// rows < 4096: Hout = A@WoT + bo + H;  rows >= 4096: Vout = A@WvoT + V (+bf16 dual)
__global__ __launch_bounds__(256) void gemm_wovo_kernel(
    const ushort* __restrict__ A,
    const ushort* __restrict__ WoTp, const ushort* __restrict__ WvoTp,
    const float* __restrict__ bo,
    const float* __restrict__ Hres, const float* __restrict__ Vres,
    float* __restrict__ Hout, float* __restrict__ Vout,
    ushort* __restrict__ Voutbf)
{
  const int K = 512;
  __shared__ ushort As[2][128*32];
  __shared__ ushort Bs[2][128*32];
  int t = threadIdx.x;
  int w = t >> 6, lane = t & 63;
  int q16 = lane & 15, quad = lane >> 4;
  int m0 = blockIdx.y * 128, n0 = blockIdx.x * 128;
  int wm = (w & 1) * 64, wn = (w >> 1) * 64;
  bool inH = (m0 < 4096);
  const ushort* Bt = inH ? WoTp : WvoTp;

  int r0 = t >> 2;
  int c0 = (t & 3) * 8;
  const ushort* Ag = A  + (size_t)(m0 + r0) * K + c0;
  const ushort* Bg = Bt + (size_t)(n0 + r0) * K + c0;
  int wb = w * 512;

  floatx4 acc[4][4];
  #pragma unroll
  for (int i = 0; i < 4; i++)
    #pragma unroll
    for (int j = 0; j < 4; j++) acc[i][j] = (floatx4){0.f,0.f,0.f,0.f};

  #define STAGE(buf, kk) do { \
    GLOAD_LDS16(Ag + (kk),                 &As[buf][wb]); \
    GLOAD_LDS16(Ag + (size_t)64*K + (kk),  &As[buf][2048 + wb]); \
    GLOAD_LDS16(Bg + (kk),                 &Bs[buf][wb]); \
    GLOAD_LDS16(Bg + (size_t)64*K + (kk),  &Bs[buf][2048 + wb]); \
  } while (0)

  STAGE(0, 0);
  __syncthreads();

  int cur = 0;
  for (int kt = 0; kt < 16; kt++) {
    if (kt + 1 < 16) STAGE(cur ^ 1, (kt + 1) * 32);
    short8 af[4], bf4[4];
    #pragma unroll
    for (int i = 0; i < 4; i++) {
      af[i]  = *(const short8*)&As[cur][(wm + i*16 + q16)*32 + quad*8];
      bf4[i] = *(const short8*)&Bs[cur][(wn + i*16 + q16)*32 + quad*8];
    }
    #pragma unroll
    for (int i = 0; i < 4; i++)
      #pragma unroll
      for (int j = 0; j < 4; j++)
        acc[i][j] = __builtin_amdgcn_mfma_f32_16x16x32_bf16(af[i], bf4[j], acc[i][j], 0, 0, 0);
    __syncthreads();
    cur ^= 1;
  }
  #undef STAGE

  float bj[4];
  #pragma unroll
  for (int j = 0; j < 4; j++)
    bj[j] = inH ? bo[n0 + wn + j*16 + q16] : 0.f;
  #pragma unroll
  for (int i = 0; i < 4; i++) {
    #pragma unroll
    for (int r = 0; r < 4; r++) {
      int row = m0 + wm + i*16 + quad*4 + r;
      #pragma unroll
      for (int j = 0; j < 4; j++) {
        int col = n0 + wn + j*16 + q16;
        float v = acc[i][j][r] + bj[j];
        if (inH) {
          size_t idx = (size_t)row * 512 + col;
          Hout[idx] = v + Hres[idx];
        } else {
          size_t idx = (size_t)(row - 4096) * 512 + col;
          float vv = v + Vres[idx];
          Vout[idx] = vv;
          Voutbf[idx] = f2bf(vv);
        }
      }
    }
  }
}

// ---- W2 GEMM, 64x128 tiles (grid 512 = 2 blocks/CU): HHb = S1@W2T + b2f ----
__global__ __launch_bounds__(256) void gemm_w2_kernel(
    const ushort* __restrict__ A, const ushort* __restrict__ Bt,
    const float* __restrict__ bias, float* __restrict__ C)
{
  const int N = 1024, K = 2048;
  __shared__ ushort As[2][64*32];    // 4 KB per buf
  __shared__ ushort Bs[2][128*32];   // 8 KB per buf
  int t = threadIdx.x;
  int w = t >> 6, lane = t & 63;
  int q16 = lane & 15, quad = lane >> 4;
  int m0 = blockIdx.y * 64, n0 = blockIdx.x * 128;
  int wm = (w & 1) * 32, wn = (w >> 1) * 64;

  int r0 = t >> 2;            // 0..63
  int c0 = (t & 3) * 8;
  const ushort* Ag = A  + (size_t)(m0 + r0) * K + c0;
  const ushort* Bg = Bt + (size_t)(n0 + r0) * K + c0;
  int wb = w * 512;

  floatx4 acc[2][4];
  #pragma unroll
  for (int i = 0; i < 2; i++)
    #pragma unroll
    for (int j = 0; j < 4; j++) acc[i][j] = (floatx4){0.f,0.f,0.f,0.f};

  #define STAGE(buf, kk) do { \
    GLOAD_LDS16(Ag + (kk),                 &As[buf][wb]); \
    GLOAD_LDS16(Bg + (kk),                 &Bs[buf][wb]); \
    GLOAD_LDS16(Bg + (size_t)64*K + (kk),  &Bs[buf][2048 + wb]); \
  } while (0)

  STAGE(0, 0);
  __syncthreads();

  int cur = 0;
  for (int kt = 0; kt < 64; kt++) {
    if (kt + 1 < 64) STAGE(cur ^ 1, (kt + 1) * 32);
    short8 af[2], bf4[4];
    #pragma unroll
    for (int i = 0; i < 2; i++)
      af[i]  = *(const short8*)&As[cur][(wm + i*16 + q16)*32 + quad*8];
    #pragma unroll
    for (int j = 0; j < 4; j++)
      bf4[j] = *(const short8*)&Bs[cur][(wn + j*16 + q16)*32 + quad*8];
    #pragma unroll
    for (int i = 0; i < 2; i++)
      #pragma unroll
      for (int j = 0; j < 4; j++)
        acc[i][j] = __builtin_amdgcn_mfma_f32_16x16x32_bf16(af[i], bf4[j], acc[i][j], 0, 0, 0);
    __syncthreads();
    cur ^= 1;
  }
  #undef STAGE

  float bj[4];
  #pragma unroll
  for (int j = 0; j < 4; j++)
    bj[j] = bias[n0 + wn + j*16 + q16];
  #pragma unroll
  for (int i = 0; i < 2; i++) {
    #pragma unroll
    for (int r = 0; r < 4; r++) {
      int row = m0 + wm + i*16 + quad*4 + r;
      #pragma unroll
      for (int j = 0; j < 4; j++) {
        int col = n0 + wn + j*16 + q16;
        C[(size_t)row * N + col] = acc[i][j][r] + bj[j];
      }
    }
  }
}

// --- fused bias, bf16, pre-scaled by log2e: Bc2 = mask ? (Db+Rb)*LOG2E : -1e30 ---
__global__ __launch_bounds__(256) void bias2_kernel(
    const float* __restrict__ Db, const float* __restrict__ Rb,
    const int* __restrict__ Mask, ushort* __restrict__ Bc2)
{
  int i2 = blockIdx.x*256 + threadIdx.x;    // < 2M (2 elems each)
  int e = i2 * 2;
  int b = e >> 20;
  int m = e & 1023;
  float2 d = *(const float2*)&Db[e];
  float2 r = *(const float2*)&Rb[e];
  ushort2 o;
  o.x = Mask[b*NSEQ + m]     ? f2bf((d.x + r.x)*LOG2E) : f2bf(-1e30f);
  o.y = Mask[b*NSEQ + m + 1] ? f2bf((d.y + r.y)*LOG2E) : f2bf(-1e30f);
  *(ushort2*)&Bc2[e] = o;
}

// ------- V_attn transpose -> bf16 Vt[b][h][d(128)][n(1024)] -------
__global__ __launch_bounds__(256) void vtrans_kernel(
    const ushort* __restrict__ QKV, const ushort* __restrict__ VVr,
    ushort* __restrict__ Vt)
{
  __shared__ float Ts[64][33];
  int t = threadIdx.x;
  int bh = blockIdx.z;          // b*16+h
  int b = bh >> 4, h = bh & 15;
  int dt = blockIdx.y;          // 0..3 -> d0
  int nt = blockIdx.x;          // 0..15 -> n0
  int d0 = dt*32, n0 = nt*64;
  #pragma unroll
  for (int i = 0; i < 2; i++) {
    int nl = (t >> 3) + i*32;
    int c4 = (t & 7)*4;
    const ushort* src;
    if (dt == 0) src = &QKV[(size_t)(b*NSEQ + n0 + nl)*4608 + 4096 + h*32 + c4];
    else { int c = dt - 1; src = &VVr[((size_t)(b*NSEQ + n0 + nl)*3 + c)*512 + h*32 + c4]; }
    ushort4 v = *(const ushort4*)src;
    Ts[nl][c4] = bf2f(v.x); Ts[nl][c4+1] = bf2f(v.y);
    Ts[nl][c4+2] = bf2f(v.z); Ts[nl][c4+3] = bf2f(v.w);
  }
  __syncthreads();
  int dl = t >> 3;              // 0..31
  int n8 = (t & 7)*8;
  ushort u[8];
  #pragma unroll
  for (int k = 0; k < 8; k++) u[k] = f2bf(Ts[n8+k][dl]);
  size_t ob = ((size_t)bh*128 + d0 + dl)*NSEQ + n0 + n8;
  ushort4 u0 = {u[0],u[1],u[2],u[3]}, u1 = {u[4],u[5],u[6],u[7]};
  *(ushort4*)&Vt[ob]     = u0;
  *(ushort4*)&Vt[ob + 4] = u1;
}

// ------------- bf16 MFMA flash attention v4 ------------------------------
// Swapped QK^T (mfma(K,Q) -> S^T): lane holds one q-row x 4 contiguous keys;
// bias reads b64 vector, P via v_cvt_pk_bf16_f32, P stores b64 vector;
// PV via 16x16x32 MFMA through the Ps LDS round-trip (full-rate).
__global__ __launch_bounds__(256, 2) void attn_mfma_kernel(
    const ushort* __restrict__ QKV,
    const ushort* __restrict__ Vt, const ushort* __restrict__ Bc2,
    ushort* __restrict__ HRES, ushort* __restrict__ VRES)
{
  __shared__ union {
    ushort q[128][136];                  // Q staging (transient) 34816 B
    struct {
      ushort k[64][136];                 // 17408 B  K tile [key][d]
      ushort v[128][72];                 // 18432 B  V tile [d][key]
      ushort bias[128][72];              // 18432 B  bias tile [qrow][key]
    } s;                                 // 54272 B
  } S;
  __shared__ ushort Ps[4][32][72];       // per-wave P (bf16) 18432 B

  int t = threadIdx.x;
  int w = t >> 6, lane = t & 63;
  int q16 = lane & 15, quad = lane >> 4;
  int h = blockIdx.x, qt = blockIdx.y, b = blockIdx.z;
  int q0 = qt * 128;

  // prefetch registers for one 64-key tile (K 16KB, V 16KB, bias 16KB)
  float4 rk0, rk1, rk2, rk3;
  float4 rv0, rv1, rv2, rv3;
  float4 rb0, rb1, rb2, rb3;
  const size_t kbase = (size_t)(b*NSEQ)*4608 + 2048 + h*128 + (t&3)*8;
  const size_t vbase = ((size_t)(b*NHEADS + h)*128 + (t>>3))*NSEQ + (t&7)*8;
  const size_t bbase = (size_t)(b*NSEQ + q0 + (t>>3))*NSEQ + (t&7)*8;
  int kr = t >> 2;   // K row this thread stages
  int kc = (t & 3)*8;
  int vr = t >> 3, vc = (t & 7)*8;

  #define LOADT(m0_) do { \
    const ushort* kp = &QKV[kbase + (size_t)((m0_) + kr)*4608]; \
    rk0 = *(const float4*)(kp +  0); \
    rk1 = *(const float4*)(kp + 32); \
    rk2 = *(const float4*)(kp + 64); \
    rk3 = *(const float4*)(kp + 96); \
    const ushort* vp = &Vt[vbase + (m0_)]; \
    rv0 = *(const float4*)(vp + (size_t) 0*NSEQ); \
    rv1 = *(const float4*)(vp + (size_t)32*NSEQ); \
    rv2 = *(const float4*)(vp + (size_t)64*NSEQ); \
    rv3 = *(const float4*)(vp + (size_t)96*NSEQ); \
    const ushort* bp2 = &Bc2[bbase + (m0_)]; \
    rb0 = *(const float4*)(bp2 + (size_t) 0*NSEQ); \
    rb1 = *(const float4*)(bp2 + (size_t)32*NSEQ); \
    rb2 = *(const float4*)(bp2 + (size_t)64*NSEQ); \
    rb3 = *(const float4*)(bp2 + (size_t)96*NSEQ); \
  } while (0)

  #define STORET() do { \
    *(float4*)&S.s.k[kr][kc +  0] = rk0; \
    *(float4*)&S.s.k[kr][kc + 32] = rk1; \
    *(float4*)&S.s.k[kr][kc + 64] = rk2; \
    *(float4*)&S.s.k[kr][kc + 96] = rk3; \
    *(float4*)&S.s.v[vr +  0][vc] = rv0; \
    *(float4*)&S.s.v[vr + 32][vc] = rv1; \
    *(float4*)&S.s.v[vr + 64][vc] = rv2; \
    *(float4*)&S.s.v[vr + 96][vc] = rv3; \
    *(float4*)&S.s.bias[vr +  0][vc] = rb0; \
    *(float4*)&S.s.bias[vr + 32][vc] = rb1; \
    *(float4*)&S.s.bias[vr + 64][vc] = rb2; \
    *(float4*)&S.s.bias[vr + 96][vc] = rb3; \
  } while (0)

  LOADT(0);   // tile-0 loads fly while we stage Q

  // ---- stage Q tile 128x128 bf16 ----
  #pragma unroll
  for (int i = 0; i < 8; i++) {
    int f = t + i*256;
    int r = f >> 4, c8 = f & 15;
    *(float4*)&S.q[r][c8*8] =
        *(const float4*)&QKV[(size_t)(b*NSEQ + q0 + r)*4608 + h*128 + c8*8];
  }
  __syncthreads();
  short8 qf[2][4];
  #pragma unroll
  for (int rg = 0; rg < 2; rg++)
    #pragma unroll
    for (int c = 0; c < 4; c++)
      qf[rg][c] = *(const short8*)&S.q[w*32 + rg*16 + q16][c*32 + quad*8];

  floatx4 o[2][8];
  #pragma unroll
  for (int rg = 0; rg < 2; rg++)
    #pragma unroll
    for (int i = 0; i < 8; i++) o[rg][i] = (floatx4){0.f,0.f,0.f,0.f};
  float l_i[2] = {0.f, 0.f};   // per-lane partial denom for qrow q16 (rg)

  #pragma unroll 1
  for (int it = 0; it < 16; it++) {
    __syncthreads();               // LDS free (iter0: Q frag reads done)
    STORET();
    if (it < 15) LOADT((it + 1) * 64);   // prefetch under compute
    __syncthreads();               // tile ready

    // ---- S^T = K Q^T (swapped): C[key][qrow], lane: col=q16=qrow,
    //      rows = keys g*16 + quad*4 + {0..3}
    floatx4 sf[2][4];
    #pragma unroll
    for (int rg = 0; rg < 2; rg++)
      #pragma unroll
      for (int g = 0; g < 4; g++) sf[rg][g] = (floatx4){0.f,0.f,0.f,0.f};
    __builtin_amdgcn_s_setprio(1);
    #pragma unroll
    for (int c = 0; c < 4; c++) {
      short8 kf[4];
      #pragma unroll
      for (int g = 0; g < 4; g++)
        kf[g] = *(const short8*)&S.s.k[g*16 + q16][c*32 + quad*8];
      #pragma unroll
      for (int rg = 0; rg < 2; rg++)
        #pragma unroll
        for (int g = 0; g < 4; g++)
          sf[rg][g] = __builtin_amdgcn_mfma_f32_16x16x32_bf16(kf[g], qf[rg][c], sf[rg][g], 0, 0, 0);
    }
    __builtin_amdgcn_s_setprio(0);

    // ---- fixed-shift softmax: vector bias read, packed bf16 convert,
    //      vector P store (keys contiguous per lane)
    #pragma unroll
    for (int rg = 0; rg < 2; rg++) {
      int brow = w*32 + rg*16 + q16;
      #pragma unroll
      for (int g = 0; g < 4; g++) {
        ushort4 bb = *(const ushort4*)&S.s.bias[brow][g*16 + quad*4];
        float p0 = exp2f(sf[rg][g][0]*F2 + bf2f(bb.x) - SM_SHIFT);
        float p1 = exp2f(sf[rg][g][1]*F2 + bf2f(bb.y) - SM_SHIFT);
        float p2 = exp2f(sf[rg][g][2]*F2 + bf2f(bb.z) - SM_SHIFT);
        float p3 = exp2f(sf[rg][g][3]*F2 + bf2f(bb.w) - SM_SHIFT);
        l_i[rg] += (p0 + p1) + (p2 + p3);
        unsigned d0, d1;
        asm("v_cvt_pk_bf16_f32 %0, %1, %2" : "=v"(d0) : "v"(p0), "v"(p1));
        asm("v_cvt_pk_bf16_f32 %0, %1, %2" : "=v"(d1) : "v"(p2), "v"(p3));
        uint2 dd = { d0, d1 };
        *(uint2*)&Ps[w][rg*16 + q16][g*16 + quad*4] = dd;
      }
    }

    // ---- P(32x64) @ V(64x128): wave-synchronous LDS round-trip ----
    short8 pf[2][2];
    #pragma unroll
    for (int rg = 0; rg < 2; rg++)
      #pragma unroll
      for (int ks = 0; ks < 2; ks++)
        pf[rg][ks] = *(const short8*)&Ps[w][rg*16 + q16][ks*32 + quad*8];
    __builtin_amdgcn_s_setprio(1);
    #pragma unroll
    for (int tt = 0; tt < 8; tt++) {
      short8 vf0 = *(const short8*)&S.s.v[tt*16 + q16][quad*8];
      short8 vf1 = *(const short8*)&S.s.v[tt*16 + q16][32 + quad*8];
      #pragma unroll
      for (int rg = 0; rg < 2; rg++) {
        o[rg][tt] = __builtin_amdgcn_mfma_f32_16x16x32_bf16(pf[rg][0], vf0, o[rg][tt], 0, 0, 0);
        o[rg][tt] = __builtin_amdgcn_mfma_f32_16x16x32_bf16(pf[rg][1], vf1, o[rg][tt], 0, 0, 0);
      }
    }
    __builtin_amdgcn_s_setprio(0);
  }
  #undef LOADT
  #undef STORET

  // ---- epilogue: reduce l across quads, redistribute per output row ----
  #pragma unroll
  for (int rg = 0; rg < 2; rg++) {
    float l = l_i[rg];
    l += __shfl_xor(l, 16);
    l += __shfl_xor(l, 32);        // lanes with q16=r hold row-r full sum
    #pragma unroll
    for (int i = 0; i < 4; i++) {
      float li = __shfl(l, quad*4 + i);   // denom for output row quad*4+i
      float inv = 1.0f / li;
      int grow = b*NSEQ + q0 + w*32 + rg*16 + quad*4 + i;
      #pragma unroll
      for (int tt = 0; tt < 2; tt++)
        HRES[(size_t)grow*512 + h*32 + tt*16 + q16] = f2bf(o[rg][tt][i] * inv);
      #pragma unroll
      for (int tt = 2; tt < 8; tt++) {
        int c = (tt - 2) >> 1;
        int jj = ((tt - 2) & 1)*16 + q16;
        VRES[((size_t)grow*3 + c)*512 + h*32 + jj] = f2bf(o[rg][tt][i] * inv);
      }
    }
  }
}

// ------------- scaler second half: ||V1||_2, bf16 out -------------
__global__ __launch_bounds__(256) void vnorm_kernel(
    const float* __restrict__ VP, ushort* __restrict__ SC)
{
  int idx = blockIdx.x*256 + threadIdx.x;   // < ROWS*512
  int row = idx >> 9;
  int d = idx & 511;
  const float* p = VP + (size_t)row*3072 + d;
  float a = p[0], b = p[1024], c = p[2048];
  SC[(size_t)row*1024 + 512 + d] = f2bf(sqrtf(a*a + b*b + c*c));
}

// ------------- final combine: H += h[:512]; V += h[512:]*V2 -------------
__global__ __launch_bounds__(256) void finale_kernel(
    const float* __restrict__ HH, const float* __restrict__ VP,
    float* __restrict__ Hout, float* __restrict__ Vout)
{
  int idx = blockIdx.x*256 + threadIdx.x;   // < (ROWS + VROWS)*512
  if (idx < ROWS*DHID) {
    int row = idx >> 9;
    int d = idx & 511;
    Hout[idx] += HH[(size_t)row*1024 + d];
  } else {
    int k = idx - ROWS*DHID;
    int r3 = k >> 9;
    int d = k & 511;
    int row = r3 / 3;
    Vout[k] += HH[(size_t)row*1024 + 512 + d] * VP[(size_t)r3*1024 + 512 + d];
  }
}

extern "C" void kernel_launch(void* const* d_in, const int* in_sizes, int n_in,
                              void* d_out, int out_size, void* d_ws, size_t ws_size,
                              hipStream_t stream)
{
  const float* H    = (const float*)d_in[0];
  const float* V    = (const float*)d_in[1];
  const float* Db   = (const float*)d_in[2];
  const float* Rb   = (const float*)d_in[3];
  const int*   Mask = (const int*)d_in[4];
  const float* g1   = (const float*)d_in[5];
  const float* be1  = (const float*)d_in[6];
  const float* Wq   = (const float*)d_in[7];
  const float* bq   = (const float*)d_in[8];
  const float* Wk   = (const float*)d_in[9];
  const float* bkk  = (const float*)d_in[10];
  const float* Wv   = (const float*)d_in[11];
  const float* bv   = (const float*)d_in[12];
  const float* Wvv  = (const float*)d_in[13];
  const float* Wo   = (const float*)d_in[14];
  const float* bo   = (const float*)d_in[15];
  const float* Wvo  = (const float*)d_in[16];
  const float* g2   = (const float*)d_in[17];
  const float* be2  = (const float*)d_in[18];
  const float* Wlv  = (const float*)d_in[19];
  const float* W1   = (const float*)d_in[20];
  const float* b1f  = (const float*)d_in[21];
  const float* W2   = (const float*)d_in[22];
  const float* b2f  = (const float*)d_in[23];

  float* Hout = (float*)d_out;                  // 4096 x 512
  float* Vout = Hout + (size_t)ROWS*DHID;       // 12288 x 512

  char* w = (char*)d_ws;
  const size_t MB = 1024*1024;
  const size_t KB = 1024;
  // weights bf16 transposed (live whole launch): [0, 15.36 MB)
  ushort* WqT  = (ushort*)(w + 0);
  ushort* WkT  = (ushort*)(w + 2048*KB);
  ushort* WvT  = (ushort*)(w + 4096*KB);
  ushort* WvvT = (ushort*)(w + 4608*KB);
  ushort* WoT  = (ushort*)(w + 5120*KB);
  ushort* WvoT = (ushort*)(w + 5632*KB);
  ushort* WlvT = (ushort*)(w + 6144*KB);
  ushort* W1T  = (ushort*)(w + 7168*KB);
  ushort* W2T  = (ushort*)(w + 11264*KB);
  float*  Bqkv = (float*)(w + 15360*KB);  // 18 KB concat bias
  // phase 1
  ushort* HNbf  = (ushort*)(w + 16*MB);   //  4MB
  ushort* QKVbf = (ushort*)(w + 20*MB);   // 36MB [4096][4608]
  ushort* VVrbf = (ushort*)(w + 56*MB);   // 12MB
  ushort* Vbf   = (ushort*)(w + 68*MB);   // 12MB
  ushort* Vtb   = (ushort*)(w + 80*MB);   // 16MB
  ushort* Bc2   = (ushort*)(w + 96*MB);   //  8MB  bf16 bias*log2e
  ushort* HRESbf = (ushort*)(w + 104*MB); //  4MB
  ushort* VRESbf = (ushort*)(w + 108*MB); // 12MB  (phase-1 peak 120 MB)
  // phase 2 (aliases dead phase-1 regions)
  ushort* Voutbf = (ushort*)(w + 20*MB);  // 12MB (QKV dead after attn)
  float*  VP     = (float*)(w + 56*MB);   // 48MB (VVr/Vbf/Vtb/Bc2 dead)
  ushort* SCbf   = (ushort*)(w + 104*MB); //  8MB
  ushort* S1bf   = (ushort*)(w + 112*MB); // 16MB (peak 128 MB)
  float*  HHb    = (float*)(w + 32*MB);   // 16MB (QKV region, dead)

  dim3 blk(256);

  // ---- weight prep: one batched launch ----
  WJobs J;
  const float* ws_[9] = {Wq, Wk, Wv, Wvv, Wo, Wvo, Wlv, W1, W2};
  ushort* wd_[9] = {WqT, WkT, WvT, WvvT, WoT, WvoT, WlvT, W1T, W2T};
  int wk_[9] = {512, 512, 512, 512, 512, 512, 512, 1024, 2048};
  int wn_[9] = {2048, 2048, 512, 512, 512, 512, 1024, 2048, 1024};
  int off = 0;
  for (int i = 0; i < 9; i++) {
    J.src[i] = ws_[i]; J.dst[i] = wd_[i]; J.K[i] = wk_[i]; J.N[i] = wn_[i];
    J.blk0[i] = off;
    off += (wn_[i] >> 6) * (wk_[i] >> 6);
  }
  J.blk0[9] = off;   // 1920
  wtrans_all_kernel<<<off, blk, 0, stream>>>(J);

  ln_kernel<1><<<ROWS, blk, 0, stream>>>(H, HNbf, DHID, g1, be1);
  conv_bf16_kernel<<<(VROWS*DHID/4)/256, blk, 0, stream>>>(V, Vbf);
  biascat_kernel<<<18, blk, 0, stream>>>(bq, bkk, bv, Bqkv);

  // fused Q|K|V GEMM: [4096,512] @ [512,4608] -> bf16 [4096][4608]
  gemm_mfma_kernel<0,1,0,1,0><<<dim3(36, 32), blk, 0, stream>>>(HNbf, WqT, Bqkv, nullptr, QKVbf, nullptr, 4096, 4608, 512);
  gemm_mfma_kernel<0,0,0,1,0><<<dim3( 4, 96), blk, 0, stream>>>(Vbf, WvvT, nullptr, nullptr, VVrbf, nullptr, 12288, 512, 512);

  bias2_kernel<<<(NBATCH*NSEQ*NSEQ/2)/256, blk, 0, stream>>>(Db, Rb, Mask, Bc2);
  vtrans_kernel<<<dim3(16, 4, 64), blk, 0, stream>>>(QKVbf, VVrbf, Vtb);

  attn_mfma_kernel<<<dim3(16, 8, 4), blk, 0, stream>>>(QKVbf, Vtb, Bc2, HRESbf, VRESbf);

  // merged Wo + Wvo (HRESbf||VRESbf contiguous [16384][512])
  gemm_wovo_kernel<<<dim3(4, 128), blk, 0, stream>>>(HRESbf, WoT, WvoT, bo, H, V, Hout, Vout, Voutbf);

  ln_kernel<1><<<ROWS, blk, 0, stream>>>(Hout, SCbf, 1024, g2, be2);
  gemm_mfma_kernel<0,0,0,0,0><<<dim3(8, 96), blk, 0, stream>>>(Voutbf, WlvT, nullptr, nullptr, VP, nullptr, 12288, 1024, 512);
  vnorm_kernel<<<(ROWS*DHID)/256, blk, 0, stream>>>(VP, SCbf);

  gemm_mfma_kernel<1,1,0,1,0><<<dim3(16, 32), blk, 0, stream>>>(SCbf, W1T, b1f, nullptr, S1bf, nullptr, 4096, 2048, 1024);
  // W2: 64x128 tiles -> 512 blocks (2/CU) instead of 256 (1/CU)
  gemm_w2_kernel<<<dim3(8, 64), blk, 0, stream>>>(S1bf, W2T, b2f, HHb);
  finale_kernel<<<((ROWS + VROWS)*DHID)/256, blk, 0, stream>>>(HHb, VP, Hout, Vout);
}